// Round 4
// baseline (399.913 us; speedup 1.0000x reference)
//
#include <hip/hip_runtime.h>
#include <hip/hip_bf16.h>

// ============================================================================
// ROUND 4 = ATTRIBUTION PROBE. Kernels are byte-identical to round 3.
// Launch sequence: phase1 x1, phase2 x3 (phase2 is idempotent given d).
//   dur_us(R4) - dur_us(R3) = 2 * (phase2 time)  -> direct measurement.
// ============================================================================

// Problem constants (from reference)
constexpr int Bn   = 16384;    // batch
constexpr int Fn   = 39;       // features per row
constexpr int NUMn = 13;       // masked slots
constexpr int En   = 64;       // embedding dim
constexpr int FDn  = 26000;    // per-feature vocab
constexpr int TV   = Fn * FDn; // 1,014,000 total vocab rows

// ---------------- Phase 1: streaming precompute d[v] = dot(emb[v], w) -------
__global__ __launch_bounds__(256, 8) void dot_precompute(
    const float* __restrict__ emb,   // [TV, 64]
    const float* __restrict__ lin_w, // [64]
    float*       __restrict__ d)     // [TV]
{
    const int lane = threadIdx.x & 63;
    const int s = lane & 15;   // element chunk (4 floats)
    const int g = lane >> 4;   // row subgroup 0..3

    const float4 w4 = *reinterpret_cast<const float4*>(lin_w + s * 4);

    const int nwaves = (gridDim.x * blockDim.x) >> 6;          // 8192
    const int wid    = (blockIdx.x * blockDim.x + threadIdx.x) >> 6;
    const int stride = nwaves * 16;                            // rows/generation

    for (int base = wid * 16; base < TV; base += stride) {
        if (base + 15 < TV) {
#pragma unroll
            for (int i = 0; i < 4; ++i) {
                const int row = base + i * 4 + g;
                const float4 v = *reinterpret_cast<const float4*>(emb + row * En + s * 4);
                float p = v.x * w4.x + v.y * w4.y + v.z * w4.z + v.w * w4.w;
                p += __shfl_xor(p, 1, 64);
                p += __shfl_xor(p, 2, 64);
                p += __shfl_xor(p, 4, 64);
                p += __shfl_xor(p, 8, 64);
                if (s == 0) d[row] = p;
            }
        } else {
#pragma unroll
            for (int i = 0; i < 4; ++i) {
                const int row = base + i * 4 + g;
                const int rc  = (row < TV) ? row : (TV - 1);
                const float4 v = *reinterpret_cast<const float4*>(emb + rc * En + s * 4);
                float p = v.x * w4.x + v.y * w4.y + v.z * w4.z + v.w * w4.w;
                p += __shfl_xor(p, 1, 64);
                p += __shfl_xor(p, 2, 64);
                p += __shfl_xor(p, 4, 64);
                p += __shfl_xor(p, 8, 64);
                if (s == 0 && row < TV) d[row] = p;
            }
        }
    }
}

// ---------------- Phase 2: per-row gather of d + scale + reduce + sigmoid ---
__global__ __launch_bounds__(256) void logits_kernel(
    const int*   __restrict__ features,    // [B*F]
    const int*   __restrict__ mask,        // [B*NUM]
    const unsigned char* __restrict__ mask_apply, // [B*NUM] bool
    const float* __restrict__ mask_value,  // [B*NUM]
    const float* __restrict__ d,           // [TV]
    const float* __restrict__ lin_b,       // [1]
    float*       __restrict__ out)         // [B]
{
    const int lane = threadIdx.x & 63;
    const int row  = blockIdx.x * (blockDim.x >> 6) + (threadIdx.x >> 6);
    if (row >= Bn) return;

    float v = 0.0f;
    if (lane < Fn) {
        const int feat = features[row * Fn + lane];
        const float dv = d[feat + lane * FDn];
        float scale = 1.0f;
#pragma unroll
        for (int n = 0; n < NUMn; ++n) {
            const int   m  = mask[row * NUMn + n];
            const bool  ap = mask_apply[row * NUMn + n] != 0;
            const float mv = mask_value[row * NUMn + n];
            if (m == lane && ap) scale *= mv;    // duplicates compose
        }
        v = scale * dv;
    }
#pragma unroll
    for (int off = 32; off > 0; off >>= 1)
        v += __shfl_down(v, off, 64);

    if (lane == 0) {
        const float logit = v + (float)Fn * lin_b[0];
        out[row] = 1.0f / (1.0f + expf(-logit));
    }
}

extern "C" void kernel_launch(void* const* d_in, const int* in_sizes, int n_in,
                              void* d_out, int out_size, void* d_ws, size_t ws_size,
                              hipStream_t stream) {
    const int*   features   = (const int*)  d_in[0];
    const int*   mask       = (const int*)  d_in[1];
    const unsigned char* mask_apply = (const unsigned char*)d_in[2];
    const float* mask_value = (const float*)d_in[3];
    const float* emb        = (const float*)d_in[4];
    const float* lin_w      = (const float*)d_in[5];
    const float* lin_b      = (const float*)d_in[6];
    float*       out        = (float*)d_out;
    float*       d          = (float*)d_ws;      // 4,056,000 B scratch

    // Phase 1 once.
    dot_precompute<<<2048, 256, 0, stream>>>(emb, lin_w, d);

    // Phase 2 three times (idempotent) -> dur delta vs R3 = 2 * P2.
    logits_kernel<<<Bn / 4, 256, 0, stream>>>(
        features, mask, mask_apply, mask_value, d, lin_b, out);
    logits_kernel<<<Bn / 4, 256, 0, stream>>>(
        features, mask, mask_apply, mask_value, d, lin_b, out);
    logits_kernel<<<Bn / 4, 256, 0, stream>>>(
        features, mask, mask_apply, mask_value, d, lin_b, out);
}

// Round 9
// 383.073 us; speedup vs baseline: 1.0440x; 1.0440x over previous
//
#include <hip/hip_runtime.h>
#include <hip/hip_bf16.h>

// Problem constants (from reference)
constexpr int Bn   = 16384;    // batch
constexpr int Fn   = 39;       // features per row
constexpr int NUMn = 13;       // masked slots
constexpr int En   = 64;       // embedding dim
constexpr int FDn  = 26000;    // per-feature vocab
constexpr int TV   = Fn * FDn; // 1,014,000 total vocab rows

// ---------------- Phase 1 v2: lane-per-row streaming dot -------------------
// Lane l owns row wid*64+l: 16 x float4 loads (consecutive lanes own
// consecutive 256-B rows -> the 16-load group covers a contiguous 16 KB
// wave-span, coalesced via L1), 64 in-lane FMAs against SGPR-resident w,
// one coalesced 4 B/lane store. No DS ops, no exec-masked stores, no
// cross-lane dependency chains - pure vmcnt pipeline.
__global__ __launch_bounds__(256, 8) void dot_precompute_v2(
    const float* __restrict__ emb,   // [TV, 64]
    const float* __restrict__ lin_w, // [64] (wave-uniform -> s_load)
    float*       __restrict__ d)     // [TV]
{
    const int lane = threadIdx.x & 63;
    const int wid  = (blockIdx.x * blockDim.x + threadIdx.x) >> 6;
    const int nw   = (gridDim.x * blockDim.x) >> 6;      // total waves (8192)

    for (int row0 = wid << 6; row0 < TV; row0 += (nw << 6)) {
        const int row = row0 + lane;
        if (row < TV) {
            const float* p = emb + (size_t)row * En;
            float4 a = make_float4(0.f, 0.f, 0.f, 0.f);
#pragma unroll
            for (int j = 0; j < 16; ++j) {
                const float4 v = *reinterpret_cast<const float4*>(p + j * 4);
                a.x = fmaf(v.x, lin_w[j * 4 + 0], a.x);
                a.y = fmaf(v.y, lin_w[j * 4 + 1], a.y);
                a.z = fmaf(v.z, lin_w[j * 4 + 2], a.z);
                a.w = fmaf(v.w, lin_w[j * 4 + 3], a.w);
            }
            d[row] = (a.x + a.y) + (a.z + a.w);
        }
    }
}

// ---------------- Phase 2: per-row gather of d + scale + reduce + sigmoid ---
// One wave per batch row; measured ~12 us total (probe R4), near its floor.
__global__ __launch_bounds__(256) void logits_kernel(
    const int*   __restrict__ features,    // [B*F]
    const int*   __restrict__ mask,        // [B*NUM]
    const unsigned char* __restrict__ mask_apply, // [B*NUM] bool
    const float* __restrict__ mask_value,  // [B*NUM]
    const float* __restrict__ d,           // [TV]
    const float* __restrict__ lin_b,       // [1]
    float*       __restrict__ out)         // [B]
{
    const int lane = threadIdx.x & 63;
    const int row  = blockIdx.x * (blockDim.x >> 6) + (threadIdx.x >> 6);
    if (row >= Bn) return;

    float v = 0.0f;
    if (lane < Fn) {
        const int feat = features[row * Fn + lane];
        const float dv = d[feat + lane * FDn];
        float scale = 1.0f;
#pragma unroll
        for (int n = 0; n < NUMn; ++n) {
            const int   m  = mask[row * NUMn + n];
            const bool  ap = mask_apply[row * NUMn + n] != 0;
            const float mv = mask_value[row * NUMn + n];
            if (m == lane && ap) scale *= mv;    // duplicates compose
        }
        v = scale * dv;
    }
#pragma unroll
    for (int off = 32; off > 0; off >>= 1)
        v += __shfl_down(v, off, 64);

    if (lane == 0) {
        const float logit = v + (float)Fn * lin_b[0];
        out[row] = 1.0f / (1.0f + expf(-logit));
    }
}

extern "C" void kernel_launch(void* const* d_in, const int* in_sizes, int n_in,
                              void* d_out, int out_size, void* d_ws, size_t ws_size,
                              hipStream_t stream) {
    const int*   features   = (const int*)  d_in[0];
    const int*   mask       = (const int*)  d_in[1];
    const unsigned char* mask_apply = (const unsigned char*)d_in[2];
    const float* mask_value = (const float*)d_in[3];
    const float* emb        = (const float*)d_in[4];
    const float* lin_w      = (const float*)d_in[5];
    const float* lin_b      = (const float*)d_in[6];
    float*       out        = (float*)d_out;
    float*       d          = (float*)d_ws;      // 4,056,000 B scratch

    // Phase 1: lane-per-row streaming precompute (2048 fat blocks, max resident)
    dot_precompute_v2<<<2048, 256, 0, stream>>>(emb, lin_w, d);

    // Phase 2: one wave per batch row
    logits_kernel<<<Bn / 4, 256, 0, stream>>>(
        features, mask, mask_apply, mask_value, d, lin_b, out);
}

// Round 10
// 334.191 us; speedup vs baseline: 1.1967x; 1.1463x over previous
//
#include <hip/hip_runtime.h>
#include <hip/hip_bf16.h>

// Problem constants (from reference)
constexpr int Bn  = 16384;   // batch
constexpr int Fn  = 39;      // features per row
constexpr int NUMn = 13;     // masked slots
constexpr int En  = 64;      // embedding dim
constexpr int FDn = 26000;   // per-feature vocab

// One wave (64 lanes) per batch row.  (Exact revert to round-1 kernel.)
//  lane split: s = lane&15 -> element chunk (float4), g = lane>>4 -> feature subgroup
//  logit[b] = sum_f scale(b,f) * dot(emb[feat+f*FD], w) + 39*bias
__global__ __launch_bounds__(256) void fused_emb_logit(
    const int*   __restrict__ features,    // [B*F]
    const int*   __restrict__ mask,        // [B*NUM]
    const unsigned char* __restrict__ mask_apply, // [B*NUM] bool (1 byte)
    const float* __restrict__ mask_value,  // [B*NUM]
    const float* __restrict__ emb,         // [F*FD, E]
    const float* __restrict__ lin_w,       // [E]
    const float* __restrict__ lin_b,       // [1]
    float*       __restrict__ out)         // [B]
{
    const int lane = threadIdx.x & 63;
    const int row  = blockIdx.x * (blockDim.x >> 6) + (threadIdx.x >> 6);
    if (row >= Bn) return;

    const int s = lane & 15;   // element sub-chunk (4 floats)
    const int g = lane >> 4;   // feature subgroup 0..3

    // ---- per-lane feature id & scatter-multiply scale for f = lane (lanes 0..38)
    int   feat  = 0;
    float scale = 1.0f;
    if (lane < Fn) {
        feat = features[row * Fn + lane];
#pragma unroll
        for (int n = 0; n < NUMn; ++n) {
            const int   m  = mask[row * NUMn + n];
            const bool  ap = mask_apply[row * NUMn + n] != 0;
            const float mv = mask_value[row * NUMn + n];
            if (m == lane && ap) scale *= mv;   // duplicates compose (scatter-mul)
        }
    }

    // ---- gather + scaled accumulate: 4 features per iteration via float4 lanes
    float4 acc = make_float4(0.f, 0.f, 0.f, 0.f);
#pragma unroll
    for (int f0 = 0; f0 < Fn; f0 += 4) {
        const int f  = f0 + g;
        const int fc = (f < Fn) ? f : (Fn - 1);            // clamp tail for safe addr
        const int fi = __shfl(feat, fc, 64);
        const float scv = __shfl(scale, fc, 64);
        const float sc  = (f < Fn) ? scv : 0.0f;

        const int base = (fi + fc * FDn) * En + s * 4;     // < 2^27, int-safe
        const float4 v = *reinterpret_cast<const float4*>(emb + base);
        acc.x = fmaf(sc, v.x, acc.x);
        acc.y = fmaf(sc, v.y, acc.y);
        acc.z = fmaf(sc, v.z, acc.z);
        acc.w = fmaf(sc, v.w, acc.w);
    }

    // ---- dot with w (each lane owns elements s*4 .. s*4+3), then 64-lane reduce
    const float4 w4 = *reinterpret_cast<const float4*>(lin_w + s * 4);
    float v = acc.x * w4.x + acc.y * w4.y + acc.z * w4.z + acc.w * w4.w;
#pragma unroll
    for (int off = 32; off > 0; off >>= 1)
        v += __shfl_down(v, off, 64);

    if (lane == 0) {
        const float logit = v + (float)Fn * lin_b[0];
        out[row] = 1.0f / (1.0f + expf(-logit));
    }
}

extern "C" void kernel_launch(void* const* d_in, const int* in_sizes, int n_in,
                              void* d_out, int out_size, void* d_ws, size_t ws_size,
                              hipStream_t stream) {
    const int*   features   = (const int*)  d_in[0];
    const int*   mask       = (const int*)  d_in[1];
    const unsigned char* mask_apply = (const unsigned char*)d_in[2];
    const float* mask_value = (const float*)d_in[3];
    const float* emb        = (const float*)d_in[4];
    const float* lin_w      = (const float*)d_in[5];
    const float* lin_b      = (const float*)d_in[6];
    float*       out        = (float*)d_out;

    // one wave per row: 4 waves/block -> B/4 blocks
    const int threads = 256;
    const int blocks  = Bn / (threads / 64);   // 4096
    fused_emb_logit<<<blocks, threads, 0, stream>>>(
        features, mask, mask_apply, mask_value, emb, lin_w, lin_b, out);
}